// Round 20
// baseline (181.157 us; speedup 1.0000x reference)
//
#include <hip/hip_runtime.h>
#include <math.h>

#define DIN 128
#define HID 64
#define BKTSH 7      // 128 nodes per coarse bucket
#define NBKTCAP 512  // max buckets (n <= 65536; src packed in 16 bits needs n <= 65536)
#define CAPC 2560    // max edges per bucket for LDS fast path

typedef _Float16 h2 __attribute__((ext_vector_type(2)));
typedef _Float16 f16x8 __attribute__((ext_vector_type(8)));
typedef float f32x4 __attribute__((ext_vector_type(4)));
typedef float f32x2 __attribute__((ext_vector_type(2)));

__device__ inline unsigned short f2h(float f) {
  return __builtin_bit_cast(unsigned short, (_Float16)f);
}
__device__ inline unsigned int pkrtz(float a, float b) {
  return __builtin_bit_cast(unsigned int, __builtin_amdgcn_cvt_pkrtz(a, b));
}
__device__ inline f16x8 bcf16x8(uint4 u) { return __builtin_bit_cast(f16x8, u); }
// pack 4 floats to int8 word, scale 32
__device__ inline unsigned int pki8(float a, float b, float c, float d) {
  int ia = (int)rintf(fminf(fmaxf(a * 32.f, -127.f), 127.f));
  int ib = (int)rintf(fminf(fmaxf(b * 32.f, -127.f), 127.f));
  int ic = (int)rintf(fminf(fmaxf(c * 32.f, -127.f), 127.f));
  int id = (int)rintf(fminf(fmaxf(d * 32.f, -127.f), 127.f));
  return (unsigned int)((ia & 255) | ((ib & 255) << 8) | ((ic & 255) << 16) |
                        ((id & 255) << 24));
}

// ---------------- CSR build: 2-level bucket sort ----------------
__global__ __launch_bounds__(256) void k_bktA(const int* __restrict__ dst,
                                              int* __restrict__ bhist,
                                              int nblkA, int E, int nbkt) {
  __shared__ int hist[NBKTCAP];
  int tid = threadIdx.x;
  for (int i = tid; i < nbkt; i += 256) hist[i] = 0;
  __syncthreads();
#pragma unroll
  for (int i = 0; i < 16; ++i) {
    int e = blockIdx.x * 4096 + i * 256 + tid;
    if (e < E) atomicAdd(&hist[dst[e] >> BKTSH], 1);
  }
  __syncthreads();
  for (int i = tid; i < nbkt; i += 256) bhist[i * nblkA + blockIdx.x] = hist[i];
}

__global__ __launch_bounds__(256) void k_bktScan1(int* __restrict__ bhist,
                                                  int* __restrict__ btot,
                                                  int nblkA, int nbkt) {
  int wv = threadIdx.x >> 6, lane = threadIdx.x & 63;
  int b = blockIdx.x * 4 + wv;
  if (b >= nbkt) return;
  int* rowp = bhist + (size_t)b * nblkA;
  int carry = 0;
  for (int base = 0; base < nblkA; base += 64) {
    int i = base + lane;
    int v = (i < nblkA) ? rowp[i] : 0;
    int incl = v;
#pragma unroll
    for (int d = 1; d < 64; d <<= 1) {
      int t = __shfl_up(incl, d, 64);
      if (lane >= d) incl += t;
    }
    if (i < nblkA) rowp[i] = carry + incl - v;
    carry += __shfl(incl, 63, 64);
  }
  if (lane == 0) btot[b] = carry;
}

__global__ __launch_bounds__(512) void k_bktScan2(const int* __restrict__ btot,
                                                  int* __restrict__ bktBase,
                                                  int* __restrict__ rowp,
                                                  int nbkt, int E, int n) {
  __shared__ int sc[512];
  int b = threadIdx.x;
  int s = (b < nbkt) ? btot[b] : 0;
  sc[b] = s;
  __syncthreads();
  for (int d = 1; d < 512; d <<= 1) {
    int v = (b >= d) ? sc[b - d] : 0;
    __syncthreads();
    sc[b] += v;
    __syncthreads();
  }
  if (b < nbkt) bktBase[b] = sc[b] - s;
  if (b == 0) {
    bktBase[nbkt] = E;
    rowp[n] = E;
  }
}

__global__ __launch_bounds__(256) void k_bktB(const int* __restrict__ src,
                                              const int* __restrict__ dst,
                                              const int* __restrict__ bpos,
                                              const int* __restrict__ bktBase,
                                              unsigned int* __restrict__ ebuf,
                                              int nblkA, int E, int nbkt) {
  __shared__ int cur[NBKTCAP];
  int tid = threadIdx.x;
  for (int i = tid; i < nbkt; i += 256)
    cur[i] = bpos[i * nblkA + blockIdx.x] + bktBase[i];
  __syncthreads();
#pragma unroll
  for (int i = 0; i < 16; ++i) {
    int e = blockIdx.x * 4096 + i * 256 + tid;
    if (e < E) {
      int d = dst[e];
      int pos = atomicAdd(&cur[d >> BKTSH], 1);
      ebuf[pos] = (unsigned int)src[e] | ((unsigned int)(d & 127) << 16);
    }
  }
}

__global__ __launch_bounds__(256) void k_bktC(const unsigned int* __restrict__ ebuf,
                                              const int* __restrict__ bktBase,
                                              int* __restrict__ rowp,
                                              int* __restrict__ srcs, int n) {
  __shared__ unsigned int rec[CAPC];
  __shared__ int outv[CAPC];
  __shared__ int hist[128];
  __shared__ int sc[128];
  __shared__ int cur2[128];
  int b = blockIdx.x;
  int tid = threadIdx.x;
  int s0 = bktBase[b], s1 = bktBase[b + 1];
  int cnt = s1 - s0;
  int nodeBase = b << BKTSH;
  if (tid < 128) hist[tid] = 0;
  __syncthreads();
  bool fast = (cnt <= CAPC);
  if (fast) {
    for (int i = tid; i < cnt; i += 256) {
      unsigned int r = ebuf[s0 + i];
      rec[i] = r;
      atomicAdd(&hist[r >> 16], 1);
    }
  } else {
    for (int i = tid; i < cnt; i += 256) atomicAdd(&hist[ebuf[s0 + i] >> 16], 1);
  }
  __syncthreads();
  if (tid < 128) sc[tid] = hist[tid];
  __syncthreads();
  for (int d = 1; d < 128; d <<= 1) {
    int v = (tid < 128 && tid >= d) ? sc[tid - d] : 0;
    __syncthreads();
    if (tid < 128) sc[tid] += v;
    __syncthreads();
  }
  if (tid < 128) {
    int excl = sc[tid] - hist[tid];
    int node = nodeBase + tid;
    if (node < n) rowp[node] = s0 + excl;
    cur2[tid] = excl;
  }
  __syncthreads();
  if (fast) {
    for (int i = tid; i < cnt; i += 256) {
      unsigned int r = rec[i];
      int pos = atomicAdd(&cur2[r >> 16], 1);
      outv[pos] = (int)(r & 0xFFFFu);
    }
    __syncthreads();
    for (int i = tid; i < cnt; i += 256) srcs[s0 + i] = outv[i];
  } else {
    for (int i = tid; i < cnt; i += 256) {
      unsigned int r = ebuf[s0 + i];
      int pos = atomicAdd(&cur2[r >> 16], 1);
      srcs[s0 + pos] = (int)(r & 0xFFFFu);
    }
  }
}

// ---------------- weight pre-pack (one kernel) ----------------
__global__ __launch_bounds__(256) void k_wpack(
    const float* __restrict__ Wq, const float* __restrict__ Wk,
    const float* __restrict__ Wv, const float* __restrict__ Wout,
    const float* __restrict__ W1, const float* __restrict__ W2,
    const float* __restrict__ emb_w, const float* __restrict__ out_w,
    uint4* __restrict__ P) {
  int t = blockIdx.x * 256 + threadIdx.x;  // 0..11647
  if (t >= 11648) return;
  if (t < 10240) {
    int layer = t / 5120;
    int r = t - layer * 5120;
    const float* W;
    int idx, nkk, ld, base;
    bool permk = false;
    if (r < 1024) {
      W = Wq + layer * 64 * 128; idx = r; nkk = 2; ld = 128; base = 0;
    } else if (r < 2048) {
      W = Wk + layer * 64 * 128; idx = r - 1024; nkk = 2; ld = 128; base = 1024;
    } else if (r < 3072) {
      W = Wv + layer * 64 * 128; idx = r - 2048; nkk = 2; ld = 128; base = 2048;
    } else if (r < 4096) {
      W = Wout + layer * 128 * 64; idx = r - 3072; nkk = 4; ld = 64; base = 3072;
      permk = true;
    } else if (r < 4608) {
      W = W1 + layer * 64 * 64; idx = r - 4096; nkk = 2; ld = 64; base = 4096;
    } else {
      W = W2 + layer * 64 * 64; idx = r - 4608; nkk = 2; ld = 64; base = 4608;
    }
    int lane = idx & 63;
    int g = idx >> 6;
    int ct = g / nkk, kk = g - ct * nkk;
    int lc = lane & 15, lg = lane >> 4;
    unsigned short o[8];
#pragma unroll
    for (int i = 0; i < 8; ++i) {
      int rr = kk * 32 + lg * 8 + i;
      if (permk) {
        int bb = rr & 63;
        rr = (rr & 64) + (bb & 3) * 16 + (bb >> 2);
      }
      o[i] = f2h(W[rr * ld + ct * 16 + lc]);
    }
    P[layer * 5120 + base + idx] = *(const uint4*)o;
  } else if (t < 11264) {
    int idx = t - 10240;
    int lane = idx & 63;
    int g = idx >> 6;
    int ct = g >> 2, kk = g & 3;
    int lc = lane & 15, lg = lane >> 4;
    unsigned short o[8];
#pragma unroll
    for (int i = 0; i < 8; ++i)
      o[i] = f2h(emb_w[(kk * 32 + lg * 8 + i) * 64 + ct * 16 + lc]);
    P[10240 + idx] = *(const uint4*)o;
  } else {
    int idx = t - 11264;
    int lane = idx & 63;
    int g = idx >> 6;
    int ct = g >> 1, kk = g & 1;
    int lc = lane & 15, lg = lane >> 4;
    int col = ct * 16 + lc;
    unsigned short o[8];
#pragma unroll
    for (int i = 0; i < 8; ++i)
      o[i] = (col < 40) ? f2h(out_w[(kk * 32 + lg * 8 + i) * 40 + col]) : (unsigned short)0;
    P[11264 + idx] = *(const uint4*)o;
  }
}

// ---------------- shared QKV MFMA body (register-prefetched B fragments) --------
__device__ inline void qkv_mfma(f16x8 af0, f16x8 af1, const uint4* __restrict__ Bq,
                                const uint4* __restrict__ Bk,
                                const uint4* __restrict__ Bv,
                                unsigned char* __restrict__ Qi8,
                                unsigned char* __restrict__ KVf8, int nb, int n,
                                int lc, int lg) {
  int lanei = lg * 16 + lc;
#pragma unroll
  for (int head = 0; head < 2; ++head) {
    uint4 bq[8], bk[8], bv[8];
#pragma unroll
    for (int i = 0; i < 8; ++i) bq[i] = Bq[(head * 8 + i) * 64 + lanei];
#pragma unroll
    for (int i = 0; i < 8; ++i) bk[i] = Bk[(head * 8 + i) * 64 + lanei];
#pragma unroll
    for (int i = 0; i < 8; ++i) bv[i] = Bv[(head * 8 + i) * 64 + lanei];
    f32x4 qa[4], ka[4], va[4];
#pragma unroll
    for (int c4 = 0; c4 < 4; ++c4) {
      f32x4 z = {};
      z = __builtin_amdgcn_mfma_f32_16x16x32_f16(af0, bcf16x8(bq[c4 * 2 + 0]), z, 0, 0, 0);
      qa[c4] = __builtin_amdgcn_mfma_f32_16x16x32_f16(af1, bcf16x8(bq[c4 * 2 + 1]), z, 0, 0, 0);
    }
#pragma unroll
    for (int c4 = 0; c4 < 4; ++c4) {
      f32x4 z = {};
      z = __builtin_amdgcn_mfma_f32_16x16x32_f16(af0, bcf16x8(bk[c4 * 2 + 0]), z, 0, 0, 0);
      ka[c4] = __builtin_amdgcn_mfma_f32_16x16x32_f16(af1, bcf16x8(bk[c4 * 2 + 1]), z, 0, 0, 0);
    }
#pragma unroll
    for (int c4 = 0; c4 < 4; ++c4) {
      f32x4 z = {};
      z = __builtin_amdgcn_mfma_f32_16x16x32_f16(af0, bcf16x8(bv[c4 * 2 + 0]), z, 0, 0, 0);
      va[c4] = __builtin_amdgcn_mfma_f32_16x16x32_f16(af1, bcf16x8(bv[c4 * 2 + 1]), z, 0, 0, 0);
    }
    int qaddr = head * 64 + lc * 4;
    int gaddr = (head * 8 + (lc >> 1)) * 16 + (lc & 1) * 4;
#pragma unroll
    for (int r = 0; r < 4; ++r) {
      unsigned int qw = pki8(qa[0][r], qa[1][r], qa[2][r], qa[3][r]);
      unsigned int kw = pki8(ka[0][r], ka[1][r], ka[2][r], ka[3][r]);
      int vw = __builtin_amdgcn_cvt_pk_fp8_f32(va[0][r], va[1][r], 0, false);
      vw = __builtin_amdgcn_cvt_pk_fp8_f32(va[2][r], va[3][r], vw, true);
      int gn = nb + lg * 4 + r;
      if (gn < n) {
        *(unsigned int*)(Qi8 + (size_t)gn * 128 + qaddr) = qw;
        *(unsigned int*)(KVf8 + (size_t)gn * 256 + gaddr) = kw;
        *(unsigned int*)(KVf8 + (size_t)gn * 256 + gaddr + 8) = (unsigned int)vw;
      }
    }
  }
}

// ---------------- fused embedding + layer-0 QKV (MFMA, 16-node tile/wave) --------
__global__ __launch_bounds__(256) void k_embqkv(
    const float* __restrict__ x, const uint4* __restrict__ Bemb,
    const float* __restrict__ emb_b, float* __restrict__ h,
    const uint4* __restrict__ Bq, const uint4* __restrict__ Bk,
    const uint4* __restrict__ Bv, unsigned char* __restrict__ Qi8,
    unsigned char* __restrict__ KVf8, int n) {
  __shared__ unsigned short red[4][16 * 88];
  int lane = threadIdx.x & 63, wv = threadIdx.x >> 6;
  int nb = (blockIdx.x * 4 + wv) * 16;
  if (nb >= n) return;
  int lc = lane & 15, lg = lane >> 4;

  uint4 be[16];
#pragma unroll
  for (int i = 0; i < 16; ++i) be[i] = Bemb[i * 64 + lane];

  int arow = (nb + lc < n) ? nb + lc : n - 1;
  const float* xr = x + (size_t)arow * 128;
  f16x8 ax[4];
#pragma unroll
  for (int kk = 0; kk < 4; ++kk) {
    float4 a = *(const float4*)(xr + kk * 32 + lg * 8);
    float4 b = *(const float4*)(xr + kk * 32 + lg * 8 + 4);
    unsigned short o[8] = {f2h(a.x), f2h(a.y), f2h(a.z), f2h(a.w),
                           f2h(b.x), f2h(b.y), f2h(b.z), f2h(b.w)};
    ax[kk] = bcf16x8(*(const uint4*)o);
  }
  f32x4 acc[4] = {};
#pragma unroll
  for (int kk = 0; kk < 4; ++kk)
#pragma unroll
    for (int ct = 0; ct < 4; ++ct)
      acc[ct] = __builtin_amdgcn_mfma_f32_16x16x32_f16(
          ax[kk], bcf16x8(be[ct * 4 + kk]), acc[ct], 0, 0, 0);
#pragma unroll
  for (int ct = 0; ct < 4; ++ct) {
    float bo = emb_b[ct * 16 + lc];
#pragma unroll
    for (int r = 0; r < 4; ++r) {
      float v = acc[ct][r] + bo;
      int gn = nb + lg * 4 + r;
      if (gn < n) h[(size_t)gn * 64 + ct * 16 + lc] = v;
      red[wv][(lg * 4 + r) * 88 + ct * 16 + lc] = f2h(v);
    }
  }
  f16x8 af0 = bcf16x8(*(const uint4*)&red[wv][lc * 88 + lg * 8]);
  f16x8 af1 = bcf16x8(*(const uint4*)&red[wv][lc * 88 + 32 + lg * 8]);
  qkv_mfma(af0, af1, Bq, Bk, Bv, Qi8, KVf8, nb, n, lc, lg);
}

// ---------------- attention gather+softmax (int8 K sdot4, fp8 V; 8-deep pipe) ----
__global__ __launch_bounds__(256) void k_attn(
    const unsigned char* __restrict__ Qi8, const unsigned char* __restrict__ KVf8,
    const int* __restrict__ row, const int* __restrict__ srcs,
    unsigned short* __restrict__ aggrh, int n) {
  int lane = threadIdx.x & 63;
  int w = threadIdx.x >> 6;
  int node = blockIdx.x * 4 + w;
  if (node >= n) return;  // no barriers in this kernel
  int sl = lane & 15, gi = lane >> 4;

  uint2 qw = *(const uint2*)(Qi8 + (size_t)node * 128 + sl * 8);
  const float SC = 0.125f * 1.44269504089f / 1024.f;

  int rs = row[node], re = row[node + 1];
  int deg = re - rs;
  float den = 0.f;
  f32x2 av0 = {0, 0}, av1 = {0, 0}, av2 = {0, 0}, av3 = {0, 0};

  if (deg > 0) {
    int iters = (deg + 3) >> 2;
    // 8-slot pipeline (r19: 4 slots left VALUBusy at 67% — latency exposed).
    // Mean iters ~4-5, so the prologue usually issues the WHOLE row's gathers.
    uint4 Kb[8];
    int sxb[8];
#pragma unroll
    for (int s = 0; s < 8; ++s) {
      if (s < iters) {
        int ei = rs + s * 4 + gi;
        int sx = (ei < re) ? srcs[ei] : srcs[rs];
        Kb[s] = *(const uint4*)(KVf8 + (size_t)sx * 256 + sl * 16);
      }
      int ei2 = rs + (s + 8) * 4 + gi;
      sxb[s] = (ei2 < re) ? srcs[ei2] : srcs[rs];
    }
    for (int it = 0; it < iters; it += 8) {
#pragma unroll
      for (int s = 0; s < 8; ++s) {
        int cit = it + s;
        if (cit < iters) {  // wave-uniform
          uint4 D = Kb[s];
          if (cit + 8 < iters) {
            Kb[s] = *(const uint4*)(KVf8 + (size_t)sxb[s] * 256 + sl * 16);
          }
          {
            int ei3 = rs + (cit + 16) * 4 + gi;
            sxb[s] = (ei3 < re) ? srcs[ei3] : srcs[rs];
          }
          int isc = __builtin_amdgcn_sdot4(
              (int)D.x, (int)qw.x,
              __builtin_amdgcn_sdot4((int)D.y, (int)qw.y, 0, false), false);
          isc += __shfl_xor(isc, 1, 64);
          isc += __shfl_xor(isc, 2, 64);
          isc += __shfl_xor(isc, 4, 64);
          bool ev = (rs + cit * 4 + gi) < re;
          float wgt = ev ? __builtin_amdgcn_exp2f((float)isc * SC) : 0.f;
          den += wgt;
          f32x2 w2 = {wgt, wgt};
          av0 += w2 * __builtin_amdgcn_cvt_pk_f32_fp8(D.z, false);
          av1 += w2 * __builtin_amdgcn_cvt_pk_f32_fp8(D.z, true);
          av2 += w2 * __builtin_amdgcn_cvt_pk_f32_fp8(D.w, false);
          av3 += w2 * __builtin_amdgcn_cvt_pk_f32_fp8(D.w, true);
        }
      }
    }
  }
#pragma unroll
  for (int d = 16; d < 64; d <<= 1) {
    den += __shfl_xor(den, d, 64);
    av0.x += __shfl_xor(av0.x, d, 64);
    av0.y += __shfl_xor(av0.y, d, 64);
    av1.x += __shfl_xor(av1.x, d, 64);
    av1.y += __shfl_xor(av1.y, d, 64);
    av2.x += __shfl_xor(av2.x, d, 64);
    av2.y += __shfl_xor(av2.y, d, 64);
    av3.x += __shfl_xor(av3.x, d, 64);
    av3.y += __shfl_xor(av3.y, d, 64);
  }
  float inv = fminf(1.f / (den + 1e-16f), 60000.f);
  if (lane < 16) {
    uint4 o;
    o.x = pkrtz(av0.x * inv, av0.y * inv);
    o.y = pkrtz(av1.x * inv, av1.y * inv);
    o.z = pkrtz(av2.x * inv, av2.y * inv);
    o.w = pkrtz(av3.x * inv, av3.y * inv);
    *(uint4*)(aggrh + (size_t)node * 128 + sl * 8) = o;  // permuted positions
  }
}

// ---------------- post (MFMA): Wout -> +res -> LN -> FFN, then:
// MODE 0: next-layer QKV.  MODE 1: logits + log_softmax.
template <int MODE>
__global__ __launch_bounds__(256) void k_post(
    const unsigned short* __restrict__ aggrh, float* __restrict__ h,
    const uint4* __restrict__ Bout, const float* __restrict__ bout,
    const float* __restrict__ lng, const float* __restrict__ lnb,
    const uint4* __restrict__ B1, const float* __restrict__ b1,
    const uint4* __restrict__ B2, const float* __restrict__ b2,
    const uint4* __restrict__ BqN, const uint4* __restrict__ BkN,
    const uint4* __restrict__ BvN, unsigned char* __restrict__ Qi8,
    unsigned char* __restrict__ KVf8,
    const uint4* __restrict__ Bo, const float* __restrict__ out_b,
    float* __restrict__ out, int n) {
  __shared__ unsigned short red[4][16 * 88];
  int lane = threadIdx.x & 63, wv = threadIdx.x >> 6;
  int nb = (blockIdx.x * 4 + wv) * 16;
  if (nb >= n) return;  // no barriers in this kernel
  int lc = lane & 15, lg = lane >> 4;

  uint4 bf[16];
#pragma unroll
  for (int i = 0; i < 16; ++i) bf[i] = Bout[i * 64 + lane];
  f32x4 acc[4] = {};
  const uint4* arow_p = (const uint4*)(aggrh + (size_t)(nb + lc) * 128);
#pragma unroll
  for (int kk = 0; kk < 4; ++kk) {
    f16x8 af = bcf16x8(arow_p[kk * 4 + lg]);
#pragma unroll
    for (int ct = 0; ct < 4; ++ct)
      acc[ct] = __builtin_amdgcn_mfma_f32_16x16x32_f16(
          af, bcf16x8(bf[ct * 4 + kk]), acc[ct], 0, 0, 0);
  }

  float x[4][4], hl[4][4];
#pragma unroll
  for (int ct = 0; ct < 4; ++ct) {
    float bo = bout[ct * 16 + lc];
#pragma unroll
    for (int r = 0; r < 4; ++r)
      x[r][ct] = acc[ct][r] + bo + h[(size_t)(nb + lg * 4 + r) * 64 + ct * 16 + lc];
  }
  float g[4], bb[4];
#pragma unroll
  for (int ct = 0; ct < 4; ++ct) {
    g[ct] = lng[ct * 16 + lc];
    bb[ct] = lnb[ct * 16 + lc];
  }
#pragma unroll
  for (int r = 0; r < 4; ++r) {
    float s = x[r][0] + x[r][1] + x[r][2] + x[r][3];
    s += __shfl_xor(s, 1, 64);
    s += __shfl_xor(s, 2, 64);
    s += __shfl_xor(s, 4, 64);
    s += __shfl_xor(s, 8, 64);
    float mu = s * (1.f / 64.f);
    float s2 = 0.f;
#pragma unroll
    for (int ct = 0; ct < 4; ++ct) {
      float xc = x[r][ct] - mu;
      s2 += xc * xc;
    }
    s2 += __shfl_xor(s2, 1, 64);
    s2 += __shfl_xor(s2, 2, 64);
    s2 += __shfl_xor(s2, 4, 64);
    s2 += __shfl_xor(s2, 8, 64);
    float inv = rsqrtf(s2 * (1.f / 64.f) + 1e-5f);
#pragma unroll
    for (int ct = 0; ct < 4; ++ct) {
      hl[r][ct] = (x[r][ct] - mu) * inv * g[ct] + bb[ct];
      red[wv][(lg * 4 + r) * 88 + ct * 16 + lc] = f2h(hl[r][ct]);
    }
  }

  uint4 b1f[8];
#pragma unroll
  for (int i = 0; i < 8; ++i) b1f[i] = B1[i * 64 + lane];
  f32x4 acc2[4] = {};
#pragma unroll
  for (int kk = 0; kk < 2; ++kk) {
    f16x8 af = bcf16x8(*(const uint4*)&red[wv][lc * 88 + kk * 32 + lg * 8]);
#pragma unroll
    for (int ct = 0; ct < 4; ++ct)
      acc2[ct] = __builtin_amdgcn_mfma_f32_16x16x32_f16(
          af, bcf16x8(b1f[ct * 2 + kk]), acc2[ct], 0, 0, 0);
  }
#pragma unroll
  for (int ct = 0; ct < 4; ++ct) {
    float b1c = b1[ct * 16 + lc];
#pragma unroll
    for (int r = 0; r < 4; ++r)
      red[wv][(lg * 4 + r) * 88 + ct * 16 + lc] = f2h(fmaxf(acc2[ct][r] + b1c, 0.f));
  }

  uint4 b2f[8];
#pragma unroll
  for (int i = 0; i < 8; ++i) b2f[i] = B2[i * 64 + lane];
  f32x4 acc3[4] = {};
#pragma unroll
  for (int kk = 0; kk < 2; ++kk) {
    f16x8 af = bcf16x8(*(const uint4*)&red[wv][lc * 88 + kk * 32 + lg * 8]);
#pragma unroll
    for (int ct = 0; ct < 4; ++ct)
      acc3[ct] = __builtin_amdgcn_mfma_f32_16x16x32_f16(
          af, bcf16x8(b2f[ct * 2 + kk]), acc3[ct], 0, 0, 0);
  }
#pragma unroll
  for (int ct = 0; ct < 4; ++ct) {
    float b2c = b2[ct * 16 + lc];
#pragma unroll
    for (int r = 0; r < 4; ++r) {
      float v = hl[r][ct] + acc3[ct][r] + b2c;
      int gn = nb + lg * 4 + r;
      if (MODE == 0 && gn < n) h[(size_t)gn * 64 + ct * 16 + lc] = v;
      red[wv][(lg * 4 + r) * 88 + ct * 16 + lc] = f2h(v);
    }
  }

  if (MODE == 0) {
    f16x8 af0 = bcf16x8(*(const uint4*)&red[wv][lc * 88 + lg * 8]);
    f16x8 af1 = bcf16x8(*(const uint4*)&red[wv][lc * 88 + 32 + lg * 8]);
    qkv_mfma(af0, af1, BqN, BkN, BvN, Qi8, KVf8, nb, n, lc, lg);
  } else {
    uint4 bof[6];
#pragma unroll
    for (int i = 0; i < 6; ++i) bof[i] = Bo[i * 64 + lane];
    f32x4 lg4[3] = {};
#pragma unroll
    for (int kk = 0; kk < 2; ++kk) {
      f16x8 af = bcf16x8(*(const uint4*)&red[wv][lc * 88 + kk * 32 + lg * 8]);
#pragma unroll
      for (int ct = 0; ct < 3; ++ct)
        lg4[ct] = __builtin_amdgcn_mfma_f32_16x16x32_f16(
            af, bcf16x8(bof[ct * 2 + kk]), lg4[ct], 0, 0, 0);
    }
    float ob0 = out_b[lc], ob1 = out_b[16 + lc];
    float ob2 = (lc < 8) ? out_b[32 + lc] : 0.f;
#pragma unroll
    for (int r = 0; r < 4; ++r) {
      float l0 = lg4[0][r] + ob0;
      float l1 = lg4[1][r] + ob1;
      float l2 = (lc < 8) ? (lg4[2][r] + ob2) : -3.0e38f;
      float m = fmaxf(fmaxf(l0, l1), l2);
      m = fmaxf(m, __shfl_xor(m, 1, 64));
      m = fmaxf(m, __shfl_xor(m, 2, 64));
      m = fmaxf(m, __shfl_xor(m, 4, 64));
      m = fmaxf(m, __shfl_xor(m, 8, 64));
      float e = __expf(l0 - m) + __expf(l1 - m) + ((lc < 8) ? __expf(l2 - m) : 0.f);
      e += __shfl_xor(e, 1, 64);
      e += __shfl_xor(e, 2, 64);
      e += __shfl_xor(e, 4, 64);
      e += __shfl_xor(e, 8, 64);
      float ls = m + logf(e);
      int gn = nb + lg * 4 + r;
      if (gn < n) {
        out[(size_t)gn * 40 + lc] = l0 - ls;
        out[(size_t)gn * 40 + 16 + lc] = l1 - ls;
        if (lc < 8) out[(size_t)gn * 40 + 32 + lc] = l2 - ls;
      }
    }
  }
}

extern "C" void kernel_launch(void* const* d_in, const int* in_sizes, int n_in,
                              void* d_out, int out_size, void* d_ws, size_t ws_size,
                              hipStream_t stream) {
  const float* x     = (const float*)d_in[0];
  const int*   ei    = (const int*)d_in[1];
  const float* emb_w = (const float*)d_in[2];
  const float* emb_b = (const float*)d_in[3];
  const float* Wq    = (const float*)d_in[4];   // [2,64,128]
  const float* Wk    = (const float*)d_in[5];
  const float* Wv    = (const float*)d_in[6];
  const float* Wout  = (const float*)d_in[7];   // [2,128,64]
  const float* bout  = (const float*)d_in[8];
  const float* ln_g  = (const float*)d_in[9];
  const float* ln_b  = (const float*)d_in[10];
  const float* W1    = (const float*)d_in[11];  // [2,64,64]
  const float* b1    = (const float*)d_in[12];
  const float* W2    = (const float*)d_in[13];
  const float* b2    = (const float*)d_in[14];
  const float* out_w = (const float*)d_in[15];  // [64,40]
  const float* out_b = (const float*)d_in[16];
  float* out = (float*)d_out;

  const int n = in_sizes[0] / DIN;  // 50000
  const int E = in_sizes[1] / 2;    // 800000

  char* ws = (char*)d_ws;
  size_t off = 0;
  auto alloc = [&](size_t bytes) {
    void* p = ws + off;
    off = (off + bytes + 255) & ~(size_t)255;
    return p;
  };
  float* h              = (float*)alloc((size_t)n * 64 * 4);
  unsigned char* Qi8    = (unsigned char*)alloc((size_t)n * 128);
  unsigned char* KVf8   = (unsigned char*)alloc((size_t)n * 256);
  unsigned short* aggrh = (unsigned short*)alloc((size_t)n * 128 * 2);
  int* rowp             = (int*)alloc((size_t)(n + 1) * 4);
  int* srcs             = (int*)alloc((size_t)E * 4);
  uint4* WP             = (uint4*)alloc((size_t)11648 * 16);
  int nblkA             = (E + 4095) / 4096;
  int nbkt              = (n + 127) >> BKTSH;
  int* bhist2           = (int*)alloc((size_t)NBKTCAP * nblkA * 4);
  int* btot             = (int*)alloc((size_t)NBKTCAP * 4);
  int* bktBase          = (int*)alloc((size_t)(NBKTCAP + 1) * 4);
  unsigned int* ebuf    = (unsigned int*)alloc((size_t)E * 4);

  const int* src = ei;
  const int* dst = ei + E;

  // CSR build via 2-level bucket sort
  k_bktA<<<nblkA, 256, 0, stream>>>(dst, bhist2, nblkA, E, nbkt);
  k_bktScan1<<<(nbkt + 3) / 4, 256, 0, stream>>>(bhist2, btot, nblkA, nbkt);
  k_bktScan2<<<1, 512, 0, stream>>>(btot, bktBase, rowp, nbkt, E, n);
  k_bktB<<<nblkA, 256, 0, stream>>>(src, dst, bhist2, bktBase, ebuf, nblkA, E, nbkt);
  k_bktC<<<nbkt, 256, 0, stream>>>(ebuf, bktBase, rowp, srcs, n);

  k_wpack<<<46, 256, 0, stream>>>(Wq, Wk, Wv, Wout, W1, W2, emb_w, out_w, WP);

  const uint4* L0 = WP;
  const uint4* L1 = WP + 5120;
  const uint4* Bemb = WP + 10240;
  const uint4* Bo = WP + 11264;

  // embedding + layer-0 QKV fused
  k_embqkv<<<(n + 63) / 64, 256, 0, stream>>>(x, Bemb, emb_b, h, L0, L0 + 1024,
                                              L0 + 2048, Qi8, KVf8, n);

  // layer 0: attn -> post(+layer-1 QKV)
  k_attn<<<(n + 3) / 4, 256, 0, stream>>>(Qi8, KVf8, rowp, srcs, aggrh, n);
  k_post<0><<<(n + 63) / 64, 256, 0, stream>>>(
      aggrh, h, L0 + 3072, bout, ln_g, ln_b, L0 + 4096, b1, L0 + 4608, b2,
      L1, L1 + 1024, L1 + 2048, Qi8, KVf8, nullptr, nullptr, nullptr, n);

  // layer 1: attn -> post(+logits/log_softmax)
  k_attn<<<(n + 3) / 4, 256, 0, stream>>>(Qi8, KVf8, rowp, srcs, aggrh, n);
  k_post<1><<<(n + 63) / 64, 256, 0, stream>>>(
      aggrh, h, L1 + 3072, bout + 64, ln_g + 64, ln_b + 64, L1 + 4096, b1 + 64,
      L1 + 4608, b2 + 64, nullptr, nullptr, nullptr, nullptr, nullptr,
      Bo, out_b, out, n);
}

// Round 21
// 172.885 us; speedup vs baseline: 1.0478x; 1.0478x over previous
//
#include <hip/hip_runtime.h>
#include <math.h>

#define DIN 128
#define HID 64
#define BKTSH 7      // 128 nodes per coarse bucket
#define NBKTCAP 512  // max buckets (n <= 65536; src packed in 16 bits needs n <= 65536)
#define CAPC 2560    // max edges per bucket for LDS fast path

typedef _Float16 h2 __attribute__((ext_vector_type(2)));
typedef _Float16 f16x8 __attribute__((ext_vector_type(8)));
typedef float f32x4 __attribute__((ext_vector_type(4)));
typedef float f32x2 __attribute__((ext_vector_type(2)));

__device__ inline unsigned short f2h(float f) {
  return __builtin_bit_cast(unsigned short, (_Float16)f);
}
__device__ inline unsigned int pkrtz(float a, float b) {
  return __builtin_bit_cast(unsigned int, __builtin_amdgcn_cvt_pkrtz(a, b));
}
__device__ inline f16x8 bcf16x8(uint4 u) { return __builtin_bit_cast(f16x8, u); }
// pack 4 floats to int8 word, scale 32
__device__ inline unsigned int pki8(float a, float b, float c, float d) {
  int ia = (int)rintf(fminf(fmaxf(a * 32.f, -127.f), 127.f));
  int ib = (int)rintf(fminf(fmaxf(b * 32.f, -127.f), 127.f));
  int ic = (int)rintf(fminf(fmaxf(c * 32.f, -127.f), 127.f));
  int id = (int)rintf(fminf(fmaxf(d * 32.f, -127.f), 127.f));
  return (unsigned int)((ia & 255) | ((ib & 255) << 8) | ((ic & 255) << 16) |
                        ((id & 255) << 24));
}

// ---------------- CSR build: 2-level bucket sort ----------------
__global__ __launch_bounds__(256) void k_bktA(const int* __restrict__ dst,
                                              int* __restrict__ bhist,
                                              int nblkA, int E, int nbkt) {
  __shared__ int hist[NBKTCAP];
  int tid = threadIdx.x;
  for (int i = tid; i < nbkt; i += 256) hist[i] = 0;
  __syncthreads();
#pragma unroll
  for (int i = 0; i < 16; ++i) {
    int e = blockIdx.x * 4096 + i * 256 + tid;
    if (e < E) atomicAdd(&hist[dst[e] >> BKTSH], 1);
  }
  __syncthreads();
  for (int i = tid; i < nbkt; i += 256) bhist[i * nblkA + blockIdx.x] = hist[i];
}

__global__ __launch_bounds__(256) void k_bktScan1(int* __restrict__ bhist,
                                                  int* __restrict__ btot,
                                                  int nblkA, int nbkt) {
  int wv = threadIdx.x >> 6, lane = threadIdx.x & 63;
  int b = blockIdx.x * 4 + wv;
  if (b >= nbkt) return;
  int* rowp = bhist + (size_t)b * nblkA;
  int carry = 0;
  for (int base = 0; base < nblkA; base += 64) {
    int i = base + lane;
    int v = (i < nblkA) ? rowp[i] : 0;
    int incl = v;
#pragma unroll
    for (int d = 1; d < 64; d <<= 1) {
      int t = __shfl_up(incl, d, 64);
      if (lane >= d) incl += t;
    }
    if (i < nblkA) rowp[i] = carry + incl - v;
    carry += __shfl(incl, 63, 64);
  }
  if (lane == 0) btot[b] = carry;
}

__global__ __launch_bounds__(512) void k_bktScan2(const int* __restrict__ btot,
                                                  int* __restrict__ bktBase,
                                                  int* __restrict__ rowp,
                                                  int nbkt, int E, int n) {
  __shared__ int sc[512];
  int b = threadIdx.x;
  int s = (b < nbkt) ? btot[b] : 0;
  sc[b] = s;
  __syncthreads();
  for (int d = 1; d < 512; d <<= 1) {
    int v = (b >= d) ? sc[b - d] : 0;
    __syncthreads();
    sc[b] += v;
    __syncthreads();
  }
  if (b < nbkt) bktBase[b] = sc[b] - s;
  if (b == 0) {
    bktBase[nbkt] = E;
    rowp[n] = E;
  }
}

__global__ __launch_bounds__(256) void k_bktB(const int* __restrict__ src,
                                              const int* __restrict__ dst,
                                              const int* __restrict__ bpos,
                                              const int* __restrict__ bktBase,
                                              unsigned int* __restrict__ ebuf,
                                              int nblkA, int E, int nbkt) {
  __shared__ int cur[NBKTCAP];
  int tid = threadIdx.x;
  for (int i = tid; i < nbkt; i += 256)
    cur[i] = bpos[i * nblkA + blockIdx.x] + bktBase[i];
  __syncthreads();
#pragma unroll
  for (int i = 0; i < 16; ++i) {
    int e = blockIdx.x * 4096 + i * 256 + tid;
    if (e < E) {
      int d = dst[e];
      int pos = atomicAdd(&cur[d >> BKTSH], 1);
      ebuf[pos] = (unsigned int)src[e] | ((unsigned int)(d & 127) << 16);
    }
  }
}

__global__ __launch_bounds__(256) void k_bktC(const unsigned int* __restrict__ ebuf,
                                              const int* __restrict__ bktBase,
                                              int* __restrict__ rowp,
                                              int* __restrict__ srcs, int n) {
  __shared__ unsigned int rec[CAPC];
  __shared__ int outv[CAPC];
  __shared__ int hist[128];
  __shared__ int sc[128];
  __shared__ int cur2[128];
  int b = blockIdx.x;
  int tid = threadIdx.x;
  int s0 = bktBase[b], s1 = bktBase[b + 1];
  int cnt = s1 - s0;
  int nodeBase = b << BKTSH;
  if (tid < 128) hist[tid] = 0;
  __syncthreads();
  bool fast = (cnt <= CAPC);
  if (fast) {
    for (int i = tid; i < cnt; i += 256) {
      unsigned int r = ebuf[s0 + i];
      rec[i] = r;
      atomicAdd(&hist[r >> 16], 1);
    }
  } else {
    for (int i = tid; i < cnt; i += 256) atomicAdd(&hist[ebuf[s0 + i] >> 16], 1);
  }
  __syncthreads();
  if (tid < 128) sc[tid] = hist[tid];
  __syncthreads();
  for (int d = 1; d < 128; d <<= 1) {
    int v = (tid < 128 && tid >= d) ? sc[tid - d] : 0;
    __syncthreads();
    if (tid < 128) sc[tid] += v;
    __syncthreads();
  }
  if (tid < 128) {
    int excl = sc[tid] - hist[tid];
    int node = nodeBase + tid;
    if (node < n) rowp[node] = s0 + excl;
    cur2[tid] = excl;
  }
  __syncthreads();
  if (fast) {
    for (int i = tid; i < cnt; i += 256) {
      unsigned int r = rec[i];
      int pos = atomicAdd(&cur2[r >> 16], 1);
      outv[pos] = (int)(r & 0xFFFFu);
    }
    __syncthreads();
    for (int i = tid; i < cnt; i += 256) srcs[s0 + i] = outv[i];
  } else {
    for (int i = tid; i < cnt; i += 256) {
      unsigned int r = ebuf[s0 + i];
      int pos = atomicAdd(&cur2[r >> 16], 1);
      srcs[s0 + pos] = (int)(r & 0xFFFFu);
    }
  }
}

// ---------------- weight pre-pack (one kernel) ----------------
__global__ __launch_bounds__(256) void k_wpack(
    const float* __restrict__ Wq, const float* __restrict__ Wk,
    const float* __restrict__ Wv, const float* __restrict__ Wout,
    const float* __restrict__ W1, const float* __restrict__ W2,
    const float* __restrict__ emb_w, const float* __restrict__ out_w,
    uint4* __restrict__ P) {
  int t = blockIdx.x * 256 + threadIdx.x;  // 0..11647
  if (t >= 11648) return;
  if (t < 10240) {
    int layer = t / 5120;
    int r = t - layer * 5120;
    const float* W;
    int idx, nkk, ld, base;
    bool permk = false;
    if (r < 1024) {
      W = Wq + layer * 64 * 128; idx = r; nkk = 2; ld = 128; base = 0;
    } else if (r < 2048) {
      W = Wk + layer * 64 * 128; idx = r - 1024; nkk = 2; ld = 128; base = 1024;
    } else if (r < 3072) {
      W = Wv + layer * 64 * 128; idx = r - 2048; nkk = 2; ld = 128; base = 2048;
    } else if (r < 4096) {
      W = Wout + layer * 128 * 64; idx = r - 3072; nkk = 4; ld = 64; base = 3072;
      permk = true;
    } else if (r < 4608) {
      W = W1 + layer * 64 * 64; idx = r - 4096; nkk = 2; ld = 64; base = 4096;
    } else {
      W = W2 + layer * 64 * 64; idx = r - 4608; nkk = 2; ld = 64; base = 4608;
    }
    int lane = idx & 63;
    int g = idx >> 6;
    int ct = g / nkk, kk = g - ct * nkk;
    int lc = lane & 15, lg = lane >> 4;
    unsigned short o[8];
#pragma unroll
    for (int i = 0; i < 8; ++i) {
      int rr = kk * 32 + lg * 8 + i;
      if (permk) {
        int bb = rr & 63;
        rr = (rr & 64) + (bb & 3) * 16 + (bb >> 2);
      }
      o[i] = f2h(W[rr * ld + ct * 16 + lc]);
    }
    P[layer * 5120 + base + idx] = *(const uint4*)o;
  } else if (t < 11264) {
    int idx = t - 10240;
    int lane = idx & 63;
    int g = idx >> 6;
    int ct = g >> 2, kk = g & 3;
    int lc = lane & 15, lg = lane >> 4;
    unsigned short o[8];
#pragma unroll
    for (int i = 0; i < 8; ++i)
      o[i] = f2h(emb_w[(kk * 32 + lg * 8 + i) * 64 + ct * 16 + lc]);
    P[10240 + idx] = *(const uint4*)o;
  } else {
    int idx = t - 11264;
    int lane = idx & 63;
    int g = idx >> 6;
    int ct = g >> 1, kk = g & 1;
    int lc = lane & 15, lg = lane >> 4;
    int col = ct * 16 + lc;
    unsigned short o[8];
#pragma unroll
    for (int i = 0; i < 8; ++i)
      o[i] = (col < 40) ? f2h(out_w[(kk * 32 + lg * 8 + i) * 40 + col]) : (unsigned short)0;
    P[11264 + idx] = *(const uint4*)o;
  }
}

// ---------------- shared QKV MFMA body (register-prefetched B fragments) --------
__device__ inline void qkv_mfma(f16x8 af0, f16x8 af1, const uint4* __restrict__ Bq,
                                const uint4* __restrict__ Bk,
                                const uint4* __restrict__ Bv,
                                unsigned char* __restrict__ Qi8,
                                unsigned char* __restrict__ KVf8, int nb, int n,
                                int lc, int lg) {
  int lanei = lg * 16 + lc;
#pragma unroll
  for (int head = 0; head < 2; ++head) {
    uint4 bq[8], bk[8], bv[8];
#pragma unroll
    for (int i = 0; i < 8; ++i) bq[i] = Bq[(head * 8 + i) * 64 + lanei];
#pragma unroll
    for (int i = 0; i < 8; ++i) bk[i] = Bk[(head * 8 + i) * 64 + lanei];
#pragma unroll
    for (int i = 0; i < 8; ++i) bv[i] = Bv[(head * 8 + i) * 64 + lanei];
    f32x4 qa[4], ka[4], va[4];
#pragma unroll
    for (int c4 = 0; c4 < 4; ++c4) {
      f32x4 z = {};
      z = __builtin_amdgcn_mfma_f32_16x16x32_f16(af0, bcf16x8(bq[c4 * 2 + 0]), z, 0, 0, 0);
      qa[c4] = __builtin_amdgcn_mfma_f32_16x16x32_f16(af1, bcf16x8(bq[c4 * 2 + 1]), z, 0, 0, 0);
    }
#pragma unroll
    for (int c4 = 0; c4 < 4; ++c4) {
      f32x4 z = {};
      z = __builtin_amdgcn_mfma_f32_16x16x32_f16(af0, bcf16x8(bk[c4 * 2 + 0]), z, 0, 0, 0);
      ka[c4] = __builtin_amdgcn_mfma_f32_16x16x32_f16(af1, bcf16x8(bk[c4 * 2 + 1]), z, 0, 0, 0);
    }
#pragma unroll
    for (int c4 = 0; c4 < 4; ++c4) {
      f32x4 z = {};
      z = __builtin_amdgcn_mfma_f32_16x16x32_f16(af0, bcf16x8(bv[c4 * 2 + 0]), z, 0, 0, 0);
      va[c4] = __builtin_amdgcn_mfma_f32_16x16x32_f16(af1, bcf16x8(bv[c4 * 2 + 1]), z, 0, 0, 0);
    }
    int qaddr = head * 64 + lc * 4;
    int gaddr = (head * 8 + (lc >> 1)) * 16 + (lc & 1) * 4;
#pragma unroll
    for (int r = 0; r < 4; ++r) {
      unsigned int qw = pki8(qa[0][r], qa[1][r], qa[2][r], qa[3][r]);
      unsigned int kw = pki8(ka[0][r], ka[1][r], ka[2][r], ka[3][r]);
      int vw = __builtin_amdgcn_cvt_pk_fp8_f32(va[0][r], va[1][r], 0, false);
      vw = __builtin_amdgcn_cvt_pk_fp8_f32(va[2][r], va[3][r], vw, true);
      int gn = nb + lg * 4 + r;
      if (gn < n) {
        *(unsigned int*)(Qi8 + (size_t)gn * 128 + qaddr) = qw;
        *(unsigned int*)(KVf8 + (size_t)gn * 256 + gaddr) = kw;
        *(unsigned int*)(KVf8 + (size_t)gn * 256 + gaddr + 8) = (unsigned int)vw;
      }
    }
  }
}

// ---------------- fused embedding + layer-0 QKV (MFMA, 16-node tile/wave) --------
__global__ __launch_bounds__(256) void k_embqkv(
    const float* __restrict__ x, const uint4* __restrict__ Bemb,
    const float* __restrict__ emb_b, float* __restrict__ h,
    const uint4* __restrict__ Bq, const uint4* __restrict__ Bk,
    const uint4* __restrict__ Bv, unsigned char* __restrict__ Qi8,
    unsigned char* __restrict__ KVf8, int n) {
  __shared__ unsigned short red[4][16 * 88];
  int lane = threadIdx.x & 63, wv = threadIdx.x >> 6;
  int nb = (blockIdx.x * 4 + wv) * 16;
  if (nb >= n) return;
  int lc = lane & 15, lg = lane >> 4;

  uint4 be[16];
#pragma unroll
  for (int i = 0; i < 16; ++i) be[i] = Bemb[i * 64 + lane];

  int arow = (nb + lc < n) ? nb + lc : n - 1;
  const float* xr = x + (size_t)arow * 128;
  f16x8 ax[4];
#pragma unroll
  for (int kk = 0; kk < 4; ++kk) {
    float4 a = *(const float4*)(xr + kk * 32 + lg * 8);
    float4 b = *(const float4*)(xr + kk * 32 + lg * 8 + 4);
    unsigned short o[8] = {f2h(a.x), f2h(a.y), f2h(a.z), f2h(a.w),
                           f2h(b.x), f2h(b.y), f2h(b.z), f2h(b.w)};
    ax[kk] = bcf16x8(*(const uint4*)o);
  }
  f32x4 acc[4] = {};
#pragma unroll
  for (int kk = 0; kk < 4; ++kk)
#pragma unroll
    for (int ct = 0; ct < 4; ++ct)
      acc[ct] = __builtin_amdgcn_mfma_f32_16x16x32_f16(
          ax[kk], bcf16x8(be[ct * 4 + kk]), acc[ct], 0, 0, 0);
#pragma unroll
  for (int ct = 0; ct < 4; ++ct) {
    float bo = emb_b[ct * 16 + lc];
#pragma unroll
    for (int r = 0; r < 4; ++r) {
      float v = acc[ct][r] + bo;
      int gn = nb + lg * 4 + r;
      if (gn < n) h[(size_t)gn * 64 + ct * 16 + lc] = v;
      red[wv][(lg * 4 + r) * 88 + ct * 16 + lc] = f2h(v);
    }
  }
  f16x8 af0 = bcf16x8(*(const uint4*)&red[wv][lc * 88 + lg * 8]);
  f16x8 af1 = bcf16x8(*(const uint4*)&red[wv][lc * 88 + 32 + lg * 8]);
  qkv_mfma(af0, af1, Bq, Bk, Bv, Qi8, KVf8, nb, n, lc, lg);
}

// ---------------- attention gather+softmax (int8 K sdot4, fp8 V; 4-slot pipe) ----
// r20 lesson: 8-slot pipeline regressed (mean iters ~4-5 -> half the slots dead,
// bigger prologue, +8 VGPR). 4 slots is the sweet spot for this degree profile.
__global__ __launch_bounds__(256) void k_attn(
    const unsigned char* __restrict__ Qi8, const unsigned char* __restrict__ KVf8,
    const int* __restrict__ row, const int* __restrict__ srcs,
    unsigned short* __restrict__ aggrh, int n) {
  int lane = threadIdx.x & 63;
  int w = threadIdx.x >> 6;
  int node = blockIdx.x * 4 + w;
  if (node >= n) return;  // no barriers in this kernel
  int sl = lane & 15, gi = lane >> 4;

  uint2 qw = *(const uint2*)(Qi8 + (size_t)node * 128 + sl * 8);
  const float SC = 0.125f * 1.44269504089f / 1024.f;

  int rs = row[node], re = row[node + 1];
  int deg = re - rs;
  float den = 0.f;
  f32x2 av0 = {0, 0}, av1 = {0, 0}, av2 = {0, 0}, av3 = {0, 0};

  if (deg > 0) {
    int iters = (deg + 3) >> 2;
    uint4 Kb[4];
    int sxb[4];
#pragma unroll
    for (int s = 0; s < 4; ++s) {
      if (s < iters) {
        int ei = rs + s * 4 + gi;
        int sx = (ei < re) ? srcs[ei] : srcs[rs];
        Kb[s] = *(const uint4*)(KVf8 + (size_t)sx * 256 + sl * 16);
      }
      int ei2 = rs + (s + 4) * 4 + gi;
      sxb[s] = (ei2 < re) ? srcs[ei2] : srcs[rs];
    }
    for (int it = 0; it < iters; it += 4) {
#pragma unroll
      for (int s = 0; s < 4; ++s) {
        int cit = it + s;
        if (cit < iters) {  // wave-uniform
          uint4 D = Kb[s];
          if (cit + 4 < iters) {
            Kb[s] = *(const uint4*)(KVf8 + (size_t)sxb[s] * 256 + sl * 16);
          }
          {
            int ei3 = rs + (cit + 8) * 4 + gi;
            sxb[s] = (ei3 < re) ? srcs[ei3] : srcs[rs];
          }
          int isc = __builtin_amdgcn_sdot4(
              (int)D.x, (int)qw.x,
              __builtin_amdgcn_sdot4((int)D.y, (int)qw.y, 0, false), false);
          isc += __shfl_xor(isc, 1, 64);
          isc += __shfl_xor(isc, 2, 64);
          isc += __shfl_xor(isc, 4, 64);
          bool ev = (rs + cit * 4 + gi) < re;
          float wgt = ev ? __builtin_amdgcn_exp2f((float)isc * SC) : 0.f;
          den += wgt;
          f32x2 w2 = {wgt, wgt};
          av0 += w2 * __builtin_amdgcn_cvt_pk_f32_fp8(D.z, false);
          av1 += w2 * __builtin_amdgcn_cvt_pk_f32_fp8(D.z, true);
          av2 += w2 * __builtin_amdgcn_cvt_pk_f32_fp8(D.w, false);
          av3 += w2 * __builtin_amdgcn_cvt_pk_f32_fp8(D.w, true);
        }
      }
    }
  }
#pragma unroll
  for (int d = 16; d < 64; d <<= 1) {
    den += __shfl_xor(den, d, 64);
    av0.x += __shfl_xor(av0.x, d, 64);
    av0.y += __shfl_xor(av0.y, d, 64);
    av1.x += __shfl_xor(av1.x, d, 64);
    av1.y += __shfl_xor(av1.y, d, 64);
    av2.x += __shfl_xor(av2.x, d, 64);
    av2.y += __shfl_xor(av2.y, d, 64);
    av3.x += __shfl_xor(av3.x, d, 64);
    av3.y += __shfl_xor(av3.y, d, 64);
  }
  float inv = fminf(1.f / (den + 1e-16f), 60000.f);
  if (lane < 16) {
    uint4 o;
    o.x = pkrtz(av0.x * inv, av0.y * inv);
    o.y = pkrtz(av1.x * inv, av1.y * inv);
    o.z = pkrtz(av2.x * inv, av2.y * inv);
    o.w = pkrtz(av3.x * inv, av3.y * inv);
    *(uint4*)(aggrh + (size_t)node * 128 + sl * 8) = o;  // permuted positions
  }
}

// ---------------- post (MFMA): Wout -> +res -> LN -> FFN, then:
// MODE 0: next-layer QKV.  MODE 1: logits + log_softmax.
template <int MODE>
__global__ __launch_bounds__(256) void k_post(
    const unsigned short* __restrict__ aggrh, float* __restrict__ h,
    const uint4* __restrict__ Bout, const float* __restrict__ bout,
    const float* __restrict__ lng, const float* __restrict__ lnb,
    const uint4* __restrict__ B1, const float* __restrict__ b1,
    const uint4* __restrict__ B2, const float* __restrict__ b2,
    const uint4* __restrict__ BqN, const uint4* __restrict__ BkN,
    const uint4* __restrict__ BvN, unsigned char* __restrict__ Qi8,
    unsigned char* __restrict__ KVf8,
    const uint4* __restrict__ Bo, const float* __restrict__ out_b,
    float* __restrict__ out, int n) {
  __shared__ unsigned short red[4][16 * 88];
  int lane = threadIdx.x & 63, wv = threadIdx.x >> 6;
  int nb = (blockIdx.x * 4 + wv) * 16;
  if (nb >= n) return;  // no barriers in this kernel
  int lc = lane & 15, lg = lane >> 4;

  uint4 bf[16];
#pragma unroll
  for (int i = 0; i < 16; ++i) bf[i] = Bout[i * 64 + lane];
  f32x4 acc[4] = {};
  const uint4* arow_p = (const uint4*)(aggrh + (size_t)(nb + lc) * 128);
#pragma unroll
  for (int kk = 0; kk < 4; ++kk) {
    f16x8 af = bcf16x8(arow_p[kk * 4 + lg]);
#pragma unroll
    for (int ct = 0; ct < 4; ++ct)
      acc[ct] = __builtin_amdgcn_mfma_f32_16x16x32_f16(
          af, bcf16x8(bf[ct * 4 + kk]), acc[ct], 0, 0, 0);
  }

  float x[4][4], hl[4][4];
#pragma unroll
  for (int ct = 0; ct < 4; ++ct) {
    float bo = bout[ct * 16 + lc];
#pragma unroll
    for (int r = 0; r < 4; ++r)
      x[r][ct] = acc[ct][r] + bo + h[(size_t)(nb + lg * 4 + r) * 64 + ct * 16 + lc];
  }
  float g[4], bb[4];
#pragma unroll
  for (int ct = 0; ct < 4; ++ct) {
    g[ct] = lng[ct * 16 + lc];
    bb[ct] = lnb[ct * 16 + lc];
  }
#pragma unroll
  for (int r = 0; r < 4; ++r) {
    float s = x[r][0] + x[r][1] + x[r][2] + x[r][3];
    s += __shfl_xor(s, 1, 64);
    s += __shfl_xor(s, 2, 64);
    s += __shfl_xor(s, 4, 64);
    s += __shfl_xor(s, 8, 64);
    float mu = s * (1.f / 64.f);
    float s2 = 0.f;
#pragma unroll
    for (int ct = 0; ct < 4; ++ct) {
      float xc = x[r][ct] - mu;
      s2 += xc * xc;
    }
    s2 += __shfl_xor(s2, 1, 64);
    s2 += __shfl_xor(s2, 2, 64);
    s2 += __shfl_xor(s2, 4, 64);
    s2 += __shfl_xor(s2, 8, 64);
    float inv = rsqrtf(s2 * (1.f / 64.f) + 1e-5f);
#pragma unroll
    for (int ct = 0; ct < 4; ++ct) {
      hl[r][ct] = (x[r][ct] - mu) * inv * g[ct] + bb[ct];
      red[wv][(lg * 4 + r) * 88 + ct * 16 + lc] = f2h(hl[r][ct]);
    }
  }

  uint4 b1f[8];
#pragma unroll
  for (int i = 0; i < 8; ++i) b1f[i] = B1[i * 64 + lane];
  f32x4 acc2[4] = {};
#pragma unroll
  for (int kk = 0; kk < 2; ++kk) {
    f16x8 af = bcf16x8(*(const uint4*)&red[wv][lc * 88 + kk * 32 + lg * 8]);
#pragma unroll
    for (int ct = 0; ct < 4; ++ct)
      acc2[ct] = __builtin_amdgcn_mfma_f32_16x16x32_f16(
          af, bcf16x8(b1f[ct * 2 + kk]), acc2[ct], 0, 0, 0);
  }
#pragma unroll
  for (int ct = 0; ct < 4; ++ct) {
    float b1c = b1[ct * 16 + lc];
#pragma unroll
    for (int r = 0; r < 4; ++r)
      red[wv][(lg * 4 + r) * 88 + ct * 16 + lc] = f2h(fmaxf(acc2[ct][r] + b1c, 0.f));
  }

  uint4 b2f[8];
#pragma unroll
  for (int i = 0; i < 8; ++i) b2f[i] = B2[i * 64 + lane];
  f32x4 acc3[4] = {};
#pragma unroll
  for (int kk = 0; kk < 2; ++kk) {
    f16x8 af = bcf16x8(*(const uint4*)&red[wv][lc * 88 + kk * 32 + lg * 8]);
#pragma unroll
    for (int ct = 0; ct < 4; ++ct)
      acc3[ct] = __builtin_amdgcn_mfma_f32_16x16x32_f16(
          af, bcf16x8(b2f[ct * 2 + kk]), acc3[ct], 0, 0, 0);
  }
#pragma unroll
  for (int ct = 0; ct < 4; ++ct) {
    float b2c = b2[ct * 16 + lc];
#pragma unroll
    for (int r = 0; r < 4; ++r) {
      float v = hl[r][ct] + acc3[ct][r] + b2c;
      int gn = nb + lg * 4 + r;
      if (MODE == 0 && gn < n) h[(size_t)gn * 64 + ct * 16 + lc] = v;
      red[wv][(lg * 4 + r) * 88 + ct * 16 + lc] = f2h(v);
    }
  }

  if (MODE == 0) {
    f16x8 af0 = bcf16x8(*(const uint4*)&red[wv][lc * 88 + lg * 8]);
    f16x8 af1 = bcf16x8(*(const uint4*)&red[wv][lc * 88 + 32 + lg * 8]);
    qkv_mfma(af0, af1, BqN, BkN, BvN, Qi8, KVf8, nb, n, lc, lg);
  } else {
    uint4 bof[6];
#pragma unroll
    for (int i = 0; i < 6; ++i) bof[i] = Bo[i * 64 + lane];
    f32x4 lg4[3] = {};
#pragma unroll
    for (int kk = 0; kk < 2; ++kk) {
      f16x8 af = bcf16x8(*(const uint4*)&red[wv][lc * 88 + kk * 32 + lg * 8]);
#pragma unroll
      for (int ct = 0; ct < 3; ++ct)
        lg4[ct] = __builtin_amdgcn_mfma_f32_16x16x32_f16(
            af, bcf16x8(bof[ct * 2 + kk]), lg4[ct], 0, 0, 0);
    }
    float ob0 = out_b[lc], ob1 = out_b[16 + lc];
    float ob2 = (lc < 8) ? out_b[32 + lc] : 0.f;
#pragma unroll
    for (int r = 0; r < 4; ++r) {
      float l0 = lg4[0][r] + ob0;
      float l1 = lg4[1][r] + ob1;
      float l2 = (lc < 8) ? (lg4[2][r] + ob2) : -3.0e38f;
      float m = fmaxf(fmaxf(l0, l1), l2);
      m = fmaxf(m, __shfl_xor(m, 1, 64));
      m = fmaxf(m, __shfl_xor(m, 2, 64));
      m = fmaxf(m, __shfl_xor(m, 4, 64));
      m = fmaxf(m, __shfl_xor(m, 8, 64));
      float e = __expf(l0 - m) + __expf(l1 - m) + ((lc < 8) ? __expf(l2 - m) : 0.f);
      e += __shfl_xor(e, 1, 64);
      e += __shfl_xor(e, 2, 64);
      e += __shfl_xor(e, 4, 64);
      e += __shfl_xor(e, 8, 64);
      float ls = m + logf(e);
      int gn = nb + lg * 4 + r;
      if (gn < n) {
        out[(size_t)gn * 40 + lc] = l0 - ls;
        out[(size_t)gn * 40 + 16 + lc] = l1 - ls;
        if (lc < 8) out[(size_t)gn * 40 + 32 + lc] = l2 - ls;
      }
    }
  }
}

extern "C" void kernel_launch(void* const* d_in, const int* in_sizes, int n_in,
                              void* d_out, int out_size, void* d_ws, size_t ws_size,
                              hipStream_t stream) {
  const float* x     = (const float*)d_in[0];
  const int*   ei    = (const int*)d_in[1];
  const float* emb_w = (const float*)d_in[2];
  const float* emb_b = (const float*)d_in[3];
  const float* Wq    = (const float*)d_in[4];   // [2,64,128]
  const float* Wk    = (const float*)d_in[5];
  const float* Wv    = (const float*)d_in[6];
  const float* Wout  = (const float*)d_in[7];   // [2,128,64]
  const float* bout  = (const float*)d_in[8];
  const float* ln_g  = (const float*)d_in[9];
  const float* ln_b  = (const float*)d_in[10];
  const float* W1    = (const float*)d_in[11];  // [2,64,64]
  const float* b1    = (const float*)d_in[12];
  const float* W2    = (const float*)d_in[13];
  const float* b2    = (const float*)d_in[14];
  const float* out_w = (const float*)d_in[15];  // [64,40]
  const float* out_b = (const float*)d_in[16];
  float* out = (float*)d_out;

  const int n = in_sizes[0] / DIN;  // 50000
  const int E = in_sizes[1] / 2;    // 800000

  char* ws = (char*)d_ws;
  size_t off = 0;
  auto alloc = [&](size_t bytes) {
    void* p = ws + off;
    off = (off + bytes + 255) & ~(size_t)255;
    return p;
  };
  float* h              = (float*)alloc((size_t)n * 64 * 4);
  unsigned char* Qi8    = (unsigned char*)alloc((size_t)n * 128);
  unsigned char* KVf8   = (unsigned char*)alloc((size_t)n * 256);
  unsigned short* aggrh = (unsigned short*)alloc((size_t)n * 128 * 2);
  int* rowp             = (int*)alloc((size_t)(n + 1) * 4);
  int* srcs             = (int*)alloc((size_t)E * 4);
  uint4* WP             = (uint4*)alloc((size_t)11648 * 16);
  int nblkA             = (E + 4095) / 4096;
  int nbkt              = (n + 127) >> BKTSH;
  int* bhist2           = (int*)alloc((size_t)NBKTCAP * nblkA * 4);
  int* btot             = (int*)alloc((size_t)NBKTCAP * 4);
  int* bktBase          = (int*)alloc((size_t)(NBKTCAP + 1) * 4);
  unsigned int* ebuf    = (unsigned int*)alloc((size_t)E * 4);

  const int* src = ei;
  const int* dst = ei + E;

  // CSR build via 2-level bucket sort
  k_bktA<<<nblkA, 256, 0, stream>>>(dst, bhist2, nblkA, E, nbkt);
  k_bktScan1<<<(nbkt + 3) / 4, 256, 0, stream>>>(bhist2, btot, nblkA, nbkt);
  k_bktScan2<<<1, 512, 0, stream>>>(btot, bktBase, rowp, nbkt, E, n);
  k_bktB<<<nblkA, 256, 0, stream>>>(src, dst, bhist2, bktBase, ebuf, nblkA, E, nbkt);
  k_bktC<<<nbkt, 256, 0, stream>>>(ebuf, bktBase, rowp, srcs, n);

  k_wpack<<<46, 256, 0, stream>>>(Wq, Wk, Wv, Wout, W1, W2, emb_w, out_w, WP);

  const uint4* L0 = WP;
  const uint4* L1 = WP + 5120;
  const uint4* Bemb = WP + 10240;
  const uint4* Bo = WP + 11264;

  // embedding + layer-0 QKV fused
  k_embqkv<<<(n + 63) / 64, 256, 0, stream>>>(x, Bemb, emb_b, h, L0, L0 + 1024,
                                              L0 + 2048, Qi8, KVf8, n);

  // layer 0: attn -> post(+layer-1 QKV)
  k_attn<<<(n + 3) / 4, 256, 0, stream>>>(Qi8, KVf8, rowp, srcs, aggrh, n);
  k_post<0><<<(n + 63) / 64, 256, 0, stream>>>(
      aggrh, h, L0 + 3072, bout, ln_g, ln_b, L0 + 4096, b1, L0 + 4608, b2,
      L1, L1 + 1024, L1 + 2048, Qi8, KVf8, nullptr, nullptr, nullptr, n);

  // layer 1: attn -> post(+logits/log_softmax)
  k_attn<<<(n + 3) / 4, 256, 0, stream>>>(Qi8, KVf8, rowp, srcs, aggrh, n);
  k_post<1><<<(n + 63) / 64, 256, 0, stream>>>(
      aggrh, h, L1 + 3072, bout + 64, ln_g + 64, ln_b + 64, L1 + 4096, b1 + 64,
      L1 + 4608, b2 + 64, nullptr, nullptr, nullptr, nullptr, nullptr,
      Bo, out_b, out, n);
}